// Round 4
// baseline (617.466 us; speedup 1.0000x reference)
//
#include <hip/hip_runtime.h>
#include <stdint.h>

typedef unsigned short u16;
typedef unsigned int u32;

// Problem constants
#define B_    2
#define S_    2048
#define NQ_   16
#define NKV_  4
#define DH_   128
#define DR_   64
#define DT_   192
#define M_    4096   // B_*S_

using short8 = __attribute__((ext_vector_type(8))) short;
using f32x4  = __attribute__((ext_vector_type(4))) float;
using half8  = __attribute__((ext_vector_type(8))) _Float16;
using u16x4  = __attribute__((ext_vector_type(4))) u16;

__device__ __forceinline__ float cl(float f) {   // clamp diagnostic: inf/NaN -> +-3.38e38 signature
    return fminf(fmaxf(f, -3.38e38f), 3.38e38f);
}
__device__ __forceinline__ u16 f2b(float f) {    // fp32 -> bf16 RNE
    union { float f; u32 u; } v; v.f = f;
    u32 u = v.u;
    return (u16)((u + 0x7fffu + ((u >> 16) & 1u)) >> 16);
}
// async global->LDS, 16B per lane. LDS dest is wave-uniform base + lane*16.
__device__ __forceinline__ void gload16(const void* g, void* l) {
    __builtin_amdgcn_global_load_lds(
        (const __attribute__((address_space(1))) void*)g,
        (__attribute__((address_space(3))) void*)l,
        16, 0, 0);
}

// ---------------------------------------------------------------------------
// x_f16: x fp32 -> fp16
// ---------------------------------------------------------------------------
__global__ __launch_bounds__(256) void x_f16(const float* __restrict__ X,
                                             _Float16* __restrict__ F) {
    size_t i = ((size_t)blockIdx.x * 256 + threadIdx.x) * 8;
    float4 a = *(const float4*)(X + i);
    float4 b4 = *(const float4*)(X + i + 4);
    float va[8] = {a.x, a.y, a.z, a.w, b4.x, b4.y, b4.z, b4.w};
    half8 f;
#pragma unroll
    for (int j = 0; j < 8; ++j) f[j] = (_Float16)va[j];
    *(half8*)(F + i) = f;
}

// ---------------------------------------------------------------------------
// Weight transpose to fp16: W[K][N] fp32 -> T [N][K] fp16.
// block (32,8), grid (K/32, N/32)
// ---------------------------------------------------------------------------
__global__ __launch_bounds__(256) void wt_f16(const float* __restrict__ W,
                                              _Float16* __restrict__ T,
                                              int K, int N) {
    __shared__ float tile[32][33];
    int k0 = blockIdx.x * 32, n0 = blockIdx.y * 32;
    int tx = threadIdx.x, ty = threadIdx.y;
#pragma unroll
    for (int i = 0; i < 32; i += 8)
        tile[ty + i][tx] = W[(size_t)(k0 + ty + i) * N + n0 + tx];
    __syncthreads();
#pragma unroll
    for (int i = 0; i < 32; i += 8)
        T[(size_t)(n0 + ty + i) * K + k0 + tx] = (_Float16)tile[tx][ty + i];
}

// ---------------------------------------------------------------------------
// fp16 single-pass MFMA GEMM. C = A[M][lda(K)] @ Bt[N][K]^T, fp32 accum.
// Tile 128x128, BK=32, 4 waves (2x2), global_load_lds staging. [verified r3]
// Epilogue modes:
//  0: p0 = fp32 C [stride N], clamped
//  1: p0 = fp16 Cf [stride N]
//  2: p0 = qb16 bf16 [m][h*192 + (n&127)], scaled by cscale (Q content)
//  3: p0 = Kp bf16 [g][s][192] cols 0..127 (n<512);
//     p1 = Vt bf16 [g][d][2048]            (n>=512)   -- fused K/V pack
//  4: n<512: p0 = ckv fp32 [m][512] (clamped) + p1 = ckf fp16 [m][512];
//     n>=512: p2 = krr fp32 [m][256]                  -- fused c_kv split
// Layouts [m89/m91 verified]: A-frag A[m=lane&15][k=quad*8+j];
// B-frag B[n=lane&15][k=quad*8+j]; C/D col=lane&15, row=quad*4+reg.
// ---------------------------------------------------------------------------
__global__ __launch_bounds__(256) void gemm_f16(const _Float16* __restrict__ A, int lda,
                                                const _Float16* __restrict__ Bt,
                                                void* __restrict__ p0,
                                                void* __restrict__ p1,
                                                void* __restrict__ p2,
                                                float cscale, int mode,
                                                int N, int K) {
    __shared__ __align__(16) _Float16 lA[128 * 32];
    __shared__ __align__(16) _Float16 lB[128 * 32];
    const int t = threadIdx.x, lane = t & 63, w = t >> 6;
    const int quad = lane >> 4, l16 = lane & 15;
    const int wr = w >> 1, wc = w & 1;
    const int m0 = blockIdx.y * 128, n0 = blockIdx.x * 128;
    f32x4 acc[4][4] = {};

    for (int kt = 0; kt < K; kt += 32) {
        __syncthreads();
#pragma unroll
        for (int c = 0; c < 2; ++c) {
            const int chunk = c * 256 + t;
            const int row = chunk >> 2, co = (chunk & 3) * 8;
            const int lofs = (c * 256 + w * 64) * 8;   // fp16 units, wave-uniform
            gload16(A + (size_t)(m0 + row) * lda + kt + co, lA + lofs);
            gload16(Bt + (size_t)(n0 + row) * K + kt + co, lB + lofs);
        }
        __syncthreads();
        half8 af[4], bf4[4];
#pragma unroll
        for (int i = 0; i < 4; ++i) {
            af[i]  = *(const half8*)&lA[(wr * 64 + i * 16 + l16) * 32 + quad * 8];
            bf4[i] = *(const half8*)&lB[(wc * 64 + i * 16 + l16) * 32 + quad * 8];
        }
#pragma unroll
        for (int i = 0; i < 4; ++i)
#pragma unroll
            for (int j = 0; j < 4; ++j)
                acc[i][j] = __builtin_amdgcn_mfma_f32_16x16x32_f16(af[i], bf4[j], acc[i][j], 0, 0, 0);
    }
#pragma unroll
    for (int i = 0; i < 4; ++i)
#pragma unroll
        for (int j = 0; j < 4; ++j) {
            const int mbase = m0 + wr * 64 + i * 16 + quad * 4;
            const int nn = n0 + wc * 64 + j * 16 + l16;
            if (mode == 0) {
                float* C = (float*)p0;
#pragma unroll
                for (int r = 0; r < 4; ++r)
                    C[(size_t)(mbase + r) * N + nn] = cl(acc[i][j][r]);
            } else if (mode == 1) {
                _Float16* Cf = (_Float16*)p0;
#pragma unroll
                for (int r = 0; r < 4; ++r)
                    Cf[(size_t)(mbase + r) * N + nn] = (_Float16)acc[i][j][r];
            } else if (mode == 2) {
                u16* Q = (u16*)p0;
                const int h = nn >> 7, dcol = nn & 127;
#pragma unroll
                for (int r = 0; r < 4; ++r)
                    Q[(size_t)(mbase + r) * 3072 + h * 192 + dcol] =
                        f2b(acc[i][j][r] * cscale);
            } else if (mode == 3) {
                const int bb = mbase >> 11, s = mbase & 2047;
                if (nn < 512) {
                    u16* Kp = (u16*)p0;
                    const int kv = nn >> 7, d = nn & 127;
                    const size_t rb = ((size_t)((bb * 4 + kv) * 2048 + s)) * 192 + d;
#pragma unroll
                    for (int r = 0; r < 4; ++r)
                        Kp[rb + (size_t)r * 192] = f2b(acc[i][j][r]);
                } else {
                    u16* Vt = (u16*)p1;
                    const int e = nn - 512, kv = e >> 7, d = e & 127;
                    u16x4 pk;
                    pk[0] = f2b(acc[i][j][0]); pk[1] = f2b(acc[i][j][1]);
                    pk[2] = f2b(acc[i][j][2]); pk[3] = f2b(acc[i][j][3]);
                    *(u16x4*)&((u16*)Vt)[((size_t)((bb * 4 + kv) * 128 + d)) * 2048 + s] = pk;
                }
            } else {   // mode 4
                if (nn < 512) {
                    float* ckv = (float*)p0;
                    _Float16* ckf = (_Float16*)p1;
#pragma unroll
                    for (int r = 0; r < 4; ++r) {
                        float v = acc[i][j][r];
                        ckv[(size_t)(mbase + r) * 512 + nn] = cl(v);
                        ckf[(size_t)(mbase + r) * 512 + nn] = (_Float16)v;
                    }
                } else {
                    float* krr = (float*)p2;
#pragma unroll
                    for (int r = 0; r < 4; ++r)
                        krr[(size_t)(mbase + r) * 256 + (nn - 512)] = acc[i][j][r];
                }
            }
        }
}

// ---------------------------------------------------------------------------
// RoPE Q: dqr fp16 [(b,s)][2560] cols 1536.. -> qb16 bf16 [(b,s)][h*192+128+d],
// pre-scaled by 1/sqrt(192).
// ---------------------------------------------------------------------------
__global__ __launch_bounds__(256) void rope_q16(const _Float16* __restrict__ dqr,
                                                const float* __restrict__ cosc,
                                                const float* __restrict__ sinc,
                                                const int* __restrict__ pos,
                                                u16* __restrict__ qb16) {
    const float sc = 0.07216878364870322f;           // 1/sqrt(192)
    int t = blockIdx.x * 256 + threadIdx.x;          // t < 4096*16*32
    int d = t & 31, h = (t >> 5) & 15, rowi = t >> 9;
    int s = rowi & 2047;
    int p = pos[s];
    float c1 = cosc[p * 64 + d],      s1 = sinc[p * 64 + d];
    float c2 = cosc[p * 64 + 32 + d], s2 = sinc[p * 64 + 32 + d];
    const _Float16* base = dqr + (size_t)rowi * 2560 + 1536 + h * 64;
    float x1 = (float)base[d];
    float x2 = (float)base[d + 32];
    u16* q = qb16 + (size_t)rowi * 3072 + h * 192 + 128;
    q[d]      = f2b((x1 * c1 - x2 * s1) * sc);
    q[d + 32] = f2b((x2 * c2 + x1 * s2) * sc);
}

// RoPE K: krr fp32 [(b,s)][256] -> Krope fp32 (Output 2) + Kp bf16 cols 128..191
__global__ __launch_bounds__(256) void rope_k(const float* __restrict__ krr,
                                              const float* __restrict__ cosc,
                                              const float* __restrict__ sinc,
                                              const int* __restrict__ pos,
                                              float* __restrict__ Krope,
                                              u16* __restrict__ Kp) {
    int t = blockIdx.x * 256 + threadIdx.x;          // t < 4096*4*32
    int d = t & 31, kv = (t >> 5) & 3, rowi = t >> 7;
    int b = rowi >> 11, s = rowi & 2047;
    int p = pos[s];
    float c1 = cosc[p * 64 + d],      s1 = sinc[p * 64 + d];
    float c2 = cosc[p * 64 + 32 + d], s2 = sinc[p * 64 + 32 + d];
    float x1 = krr[(size_t)rowi * 256 + kv * 64 + d];
    float x2 = krr[(size_t)rowi * 256 + kv * 64 + 32 + d];
    float o1 = x1 * c1 - x2 * s1;
    float o2 = x2 * c2 + x1 * s2;
    int g = b * NKV_ + kv;
    size_t ob = ((size_t)(g * S_) + s) * 64;
    Krope[ob + d]      = cl(o1);
    Krope[ob + 32 + d] = cl(o2);
    u16* kp = Kp + ((size_t)(g * S_ + s)) * 192 + 128;
    kp[d]      = f2b(o1);
    kp[32 + d] = f2b(o2);
}

// ---------------------------------------------------------------------------
// MFMA flash attention. Block = 4 waves = 64 q-rows of one (b,h), one q-tile.
// grid (32, 16, 2) = 1024 blocks; qt = 31-px (heavy blocks dispatch first).
// LDS 52KB -> 3 blocks/CU (12 waves/CU) for VALU/MFMA cross-wave overlap.
// Q from qb16 bf16 [(b,s)][h*192+k], pre-scaled by 1/sqrt(192).
// Out: atf fp16 [(b,s)][h*128+d].
// Layouts [m89/m91 verified]: A-frag A[m=lane&15][k=quad*8+j];
// B-frag B[n=lane&15][k=quad*8+j]; C/D col=lane&15, row=quad*4+reg.
// ---------------------------------------------------------------------------
__global__ __launch_bounds__(256) void attn_mfma(const u16* __restrict__ qb16,
                                                 const u16* __restrict__ Kp,
                                                 const u16* __restrict__ Vt,
                                                 _Float16* __restrict__ atf) {
    __shared__ __align__(16) u16 lK[64 * 200];     // 64 kv-rows x 192 (+8 pad)
    __shared__ __align__(16) u16 lVt[128 * 72];    // 128 d-rows x 64 (+8 pad)
    __shared__ __align__(16) u16 lP[4][16 * 72];   // per-wave P 16x64 (+8 pad)

    const int t = threadIdx.x, lane = t & 63, w = t >> 6;
    const int quad = lane >> 4, l16 = lane & 15;
    const int qt = 31 - (int)blockIdx.x;           // heavy first
    const int h = blockIdx.y, b = blockIdx.z;
    const int g = b * NKV_ + (h >> 2);
    const int q0 = qt * 64;
    const int iw = q0 + w * 16;                    // wave's q-row base

    // Q fragments: rows m=l16, contiguous 192-col row in qb16 (pre-scaled bf16)
    short8 qf[6];
    {
        const u16* qp = qb16 + ((size_t)(b * S_ + iw + l16)) * 3072 + h * 192;
#pragma unroll
        for (int kc = 0; kc < 6; ++kc)
            qf[kc] = *(const short8*)&qp[kc * 32 + quad * 8];
    }

    f32x4 O8[8] = {};                              // O: n-chunks of d (8 x 16), C layout
    float mr[4] = {-1e30f, -1e30f, -1e30f, -1e30f};
    float lr[4] = {0.f, 0.f, 0.f, 0.f};

    const int ntile = qt + 1;
    for (int tile = 0; tile < ntile; ++tile) {
        const int j0 = tile * 64;
        __syncthreads();
        // stage K tile: 64 rows x 192 u16 = 1536 x 16B, 6/thread
#pragma unroll
        for (int c = 0; c < 6; ++c) {
            int seg = c * 256 + t;
            int row = seg / 24, ch = (seg % 24) * 8;
            *(uint4*)&lK[row * 200 + ch] =
                *(const uint4*)&Kp[((size_t)g * S_ + j0 + row) * 192 + ch];
        }
        // stage Vt tile: 128 d-rows x 64 u16 = 1024 x 16B, 4/thread
#pragma unroll
        for (int c = 0; c < 4; ++c) {
            int seg = c * 256 + t;
            int d = seg >> 3, ch = (seg & 7) * 8;
            *(uint4*)&lVt[d * 72 + ch] =
                *(const uint4*)&Vt[((size_t)g * 128 + d) * S_ + j0 + ch];
        }
        __syncthreads();

        // S = Q K^T, four 16-col chunks
        f32x4 s4[4];
        __builtin_amdgcn_s_setprio(1);
#pragma unroll
        for (int cc = 0; cc < 4; ++cc) {
            f32x4 sx = {};
#pragma unroll
            for (int kc = 0; kc < 6; ++kc) {
                short8 kf = *(const short8*)&lK[(cc * 16 + l16) * 200 + kc * 32 + quad * 8];
                sx = __builtin_amdgcn_mfma_f32_16x16x32_bf16(qf[kc], kf, sx, 0, 0, 0);
            }
            s4[cc] = sx;
        }
        __builtin_amdgcn_s_setprio(0);

        // causal mask; rows ir = iw + quad*4 + r, cols j0 + cc*16 + l16
        float sv[4][4];
#pragma unroll
        for (int cc = 0; cc < 4; ++cc)
#pragma unroll
            for (int r = 0; r < 4; ++r) {
                int ir = iw + quad * 4 + r;
                sv[cc][r] = (j0 + cc * 16 + l16 <= ir) ? s4[cc][r] : -1e30f;
            }
        float tm[4];
#pragma unroll
        for (int r = 0; r < 4; ++r)
            tm[r] = fmaxf(fmaxf(sv[0][r], sv[1][r]), fmaxf(sv[2][r], sv[3][r]));
#pragma unroll
        for (int m = 1; m < 16; m <<= 1)
#pragma unroll
            for (int r = 0; r < 4; ++r) tm[r] = fmaxf(tm[r], __shfl_xor(tm[r], m));
        float al[4];
#pragma unroll
        for (int r = 0; r < 4; ++r) {
            float mn = fmaxf(mr[r], tm[r]);
            al[r] = __expf(mr[r] - mn);
            mr[r] = mn;
        }
        float p[4][4], ps[4] = {0.f, 0.f, 0.f, 0.f};
#pragma unroll
        for (int cc = 0; cc < 4; ++cc)
#pragma unroll
            for (int r = 0; r < 4; ++r) {
                p[cc][r] = __expf(sv[cc][r] - mr[r]);
                ps[r] += p[cc][r];
            }
#pragma unroll
        for (int m = 1; m < 16; m <<= 1)
#pragma unroll
            for (int r = 0; r < 4; ++r) ps[r] += __shfl_xor(ps[r], m);
#pragma unroll
        for (int r = 0; r < 4; ++r) lr[r] = lr[r] * al[r] + ps[r];
#pragma unroll
        for (int dc = 0; dc < 8; ++dc)
#pragma unroll
            for (int r = 0; r < 4; ++r) O8[dc][r] *= al[r];
        // P (C layout) -> LDS -> A-layout frags (k = 0..31, 32..63)
#pragma unroll
        for (int cc = 0; cc < 4; ++cc)
#pragma unroll
            for (int r = 0; r < 4; ++r)
                lP[w][(quad * 4 + r) * 72 + cc * 16 + l16] = f2b(p[cc][r]);
        short8 pf0 = *(const short8*)&lP[w][l16 * 72 + quad * 8];
        short8 pf1 = *(const short8*)&lP[w][l16 * 72 + 32 + quad * 8];
        // O += P V  (B-frag from Vt rows: n=d, k=kv-pos)
        __builtin_amdgcn_s_setprio(1);
#pragma unroll
        for (int dc = 0; dc < 8; ++dc) {
            short8 vf0 = *(const short8*)&lVt[(dc * 16 + l16) * 72 + quad * 8];
            short8 vf1 = *(const short8*)&lVt[(dc * 16 + l16) * 72 + 32 + quad * 8];
            O8[dc] = __builtin_amdgcn_mfma_f32_16x16x32_bf16(pf0, vf0, O8[dc], 0, 0, 0);
            O8[dc] = __builtin_amdgcn_mfma_f32_16x16x32_bf16(pf1, vf1, O8[dc], 0, 0, 0);
        }
        __builtin_amdgcn_s_setprio(0);
    }
    // epilogue: normalize, write fp16
    float inv[4];
#pragma unroll
    for (int r = 0; r < 4; ++r) inv[r] = 1.f / fmaxf(lr[r], 1e-30f);
#pragma unroll
    for (int dc = 0; dc < 8; ++dc)
#pragma unroll
        for (int r = 0; r < 4; ++r) {
            int ir = iw + quad * 4 + r;
            atf[((size_t)(b * S_ + ir)) * 2048 + h * 128 + dc * 16 + l16] =
                (_Float16)cl(O8[dc][r] * inv[r]);
        }
}

// ---------------------------------------------------------------------------
extern "C" void kernel_launch(void* const* d_in, const int* in_sizes, int n_in,
                              void* d_out, int out_size, void* d_ws, size_t ws_size,
                              hipStream_t stream) {
    const float* x     = (const float*)d_in[0];
    const float* cosc  = (const float*)d_in[1];
    const float* sinc  = (const float*)d_in[2];
    const int*   pos   = (const int*)d_in[3];
    // d_in[4] = attn_mask (causal tril) -- implemented analytically
    const float* W_DKV = (const float*)d_in[5];
    const float* W_UK  = (const float*)d_in[6];
    const float* W_UV  = (const float*)d_in[7];
    const float* W_DQ  = (const float*)d_in[8];
    const float* W_UQ  = (const float*)d_in[9];
    const float* W_KR  = (const float*)d_in[10];
    const float* W_QR  = (const float*)d_in[11];
    const float* W_O   = (const float*)d_in[12];
    (void)ws_size;

    float* outp      = (float*)d_out;            // [B,S,2048]
    float* ckv_out   = outp + 8388608;           // [B,S,512]
    float* krope_out = outp + 10485760;          // [B,NKV,S,64]

    // ---- workspace (~128 MB) ----
    char* w = (char*)d_ws;
    auto alloc = [&](size_t bytes) { char* p = w; w += bytes; return p; };
    _Float16* xf   = (_Float16*)alloc(16777216);  // x fp16 [4096][2048]
    _Float16* ckf  = (_Float16*)alloc(4194304);   // c_kv fp16 [4096][512]
    float*    krr  = (float*)alloc(4194304);      // K-rope raw fp32 [4096][256]
    _Float16* dqr  = (_Float16*)alloc(20971520);  // c_q | q_rope_raw fp16 [4096][2560]
    u16*      qb16 = (u16*)alloc(25165824);       // Q bf16 pre-scaled [4096][16][192]
    u16*      Kp   = (u16*)alloc(6291456);        // [8][2048][192] bf16
    u16*      Vt   = (u16*)alloc(4194304);        // [8][128][2048] bf16
    _Float16* atf  = (_Float16*)alloc(16777216);  // attn out fp16 [4096][2048]
    _Float16* Wdkr = (_Float16*)alloc(3145728);   // [768][2048]  (DKV|KR)
    _Float16* Wdqr = (_Float16*)alloc(10485760);  // [2560][2048] (DQ|QR)
    _Float16* Wuq  = (_Float16*)alloc(6291456);   // [2048][1536]
    _Float16* Wukv = (_Float16*)alloc(1048576);   // [1024][512]  (UK|UV)
    _Float16* Wo   = (_Float16*)alloc(8388608);   // [2048][2048]

    const float sc = 0.07216878364870322f;        // 1/sqrt(192)
    const dim3 tb(32, 8);

    // input / weight prep (fp16)
    x_f16<<<4096, 256, 0, stream>>>(x, xf);
    wt_f16<<<dim3(64, 16), tb, 0, stream>>>(W_DKV, Wdkr, 2048, 512);
    wt_f16<<<dim3(64, 8),  tb, 0, stream>>>(W_KR,  Wdkr + (size_t)512 * 2048, 2048, 256);
    wt_f16<<<dim3(64, 48), tb, 0, stream>>>(W_DQ,  Wdqr, 2048, 1536);
    wt_f16<<<dim3(64, 32), tb, 0, stream>>>(W_QR,  Wdqr + (size_t)1536 * 2048, 2048, 1024);
    wt_f16<<<dim3(48, 64), tb, 0, stream>>>(W_UQ,  Wuq, 1536, 2048);
    wt_f16<<<dim3(16, 16), tb, 0, stream>>>(W_UK,  Wukv, 512, 512);
    wt_f16<<<dim3(16, 16), tb, 0, stream>>>(W_UV,  Wukv + (size_t)512 * 512, 512, 512);
    wt_f16<<<dim3(64, 64), tb, 0, stream>>>(W_O,   Wo, 2048, 2048);

    // c_kv (Output 1, fp32) + ckf fp16 + K-rope-raw, one fused GEMM
    gemm_f16<<<dim3(6, 32), 256, 0, stream>>>(xf, 2048, Wdkr,
                                              ckv_out, ckf, krr, 1.f, 4, 768, 2048);
    // c_q | q_rope_raw, one merged GEMM
    gemm_f16<<<dim3(20, 32), 256, 0, stream>>>(xf, 2048, Wdqr,
                                               dqr, nullptr, nullptr, 1.f, 1, 2560, 2048);
    // Q content -> qb16 (bf16, pre-scaled)
    gemm_f16<<<dim3(16, 32), 256, 0, stream>>>(dqr, 2560, Wuq,
                                               qb16, nullptr, nullptr, sc, 2, 2048, 1536);
    // K content -> Kp cols 0..127 and V -> Vt, fused pack/transpose
    gemm_f16<<<dim3(8, 32), 256, 0, stream>>>(ckf, 512, Wukv,
                                              Kp, Vt, nullptr, 1.f, 3, 1024, 512);

    // rope: Q -> qb16 cols 128..191; K -> Output 2 + Kp cols 128..191
    rope_q16<<<8192, 256, 0, stream>>>(dqr, cosc, sinc, pos, qb16);
    rope_k<<<2048, 256, 0, stream>>>(krr, cosc, sinc, pos, krope_out, Kp);

    // attention + output projection
    attn_mfma<<<dim3(32, 16, 2), 256, 0, stream>>>(qb16, Kp, Vt, atf);
    gemm_f16<<<dim3(16, 32), 256, 0, stream>>>(atf, 2048, Wo,
                                               outp, nullptr, nullptr, 1.f, 0, 2048, 2048);
}

// Round 5
// 526.397 us; speedup vs baseline: 1.1730x; 1.1730x over previous
//
#include <hip/hip_runtime.h>
#include <stdint.h>

typedef unsigned short u16;
typedef unsigned int u32;

// Problem constants
#define B_    2
#define S_    2048
#define NQ_   16
#define NKV_  4
#define DH_   128
#define DR_   64
#define DT_   192
#define M_    4096   // B_*S_

using short8 = __attribute__((ext_vector_type(8))) short;
using f32x4  = __attribute__((ext_vector_type(4))) float;
using half8  = __attribute__((ext_vector_type(8))) _Float16;
using u16x4  = __attribute__((ext_vector_type(4))) u16;

__device__ __forceinline__ float cl(float f) {   // clamp diagnostic: inf/NaN -> +-3.38e38 signature
    return fminf(fmaxf(f, -3.38e38f), 3.38e38f);
}
__device__ __forceinline__ u16 f2b(float f) {    // fp32 -> bf16 RNE
    union { float f; u32 u; } v; v.f = f;
    u32 u = v.u;
    return (u16)((u + 0x7fffu + ((u >> 16) & 1u)) >> 16);
}
// async global->LDS, 16B per lane. LDS dest is wave-uniform base + lane*16.
__device__ __forceinline__ void gload16(const void* g, void* l) {
    __builtin_amdgcn_global_load_lds(
        (const __attribute__((address_space(1))) void*)g,
        (__attribute__((address_space(3))) void*)l,
        16, 0, 0);
}

// ---------------------------------------------------------------------------
// x_f16: x fp32 -> fp16
// ---------------------------------------------------------------------------
__global__ __launch_bounds__(256) void x_f16(const float* __restrict__ X,
                                             _Float16* __restrict__ F) {
    size_t i = ((size_t)blockIdx.x * 256 + threadIdx.x) * 8;
    float4 a = *(const float4*)(X + i);
    float4 b4 = *(const float4*)(X + i + 4);
    float va[8] = {a.x, a.y, a.z, a.w, b4.x, b4.y, b4.z, b4.w};
    half8 f;
#pragma unroll
    for (int j = 0; j < 8; ++j) f[j] = (_Float16)va[j];
    *(half8*)(F + i) = f;
}

// ---------------------------------------------------------------------------
// Weight transpose to fp16: W[K][N] fp32 -> T [N][K] fp16.
// block (32,8), grid (K/32, N/32)
// ---------------------------------------------------------------------------
__global__ __launch_bounds__(256) void wt_f16(const float* __restrict__ W,
                                              _Float16* __restrict__ T,
                                              int K, int N) {
    __shared__ float tile[32][33];
    int k0 = blockIdx.x * 32, n0 = blockIdx.y * 32;
    int tx = threadIdx.x, ty = threadIdx.y;
#pragma unroll
    for (int i = 0; i < 32; i += 8)
        tile[ty + i][tx] = W[(size_t)(k0 + ty + i) * N + n0 + tx];
    __syncthreads();
#pragma unroll
    for (int i = 0; i < 32; i += 8)
        T[(size_t)(n0 + ty + i) * K + k0 + tx] = (_Float16)tile[tx][ty + i];
}

// ---------------------------------------------------------------------------
// fp16 single-pass MFMA GEMM. C = A[M][lda(K)] @ Bt[N][K]^T, fp32 accum.
// Tile 128x128, BK=32, 4 waves (2x2), global_load_lds staging. [verified r3/r4]
// Epilogue modes:
//  0: p0 = fp32 C [stride N], clamped
//  1: p0 = fp16 Cf [stride N]
//  2: p0 = qb16 bf16 [m][h*192 + (n&127)], scaled by cscale (Q content)
//  3: p0 = Kp bf16 [g][s][192] cols 0..127 (n<512);
//     p1 = Vt bf16 [g][d][2048]            (n>=512)   -- fused K/V pack
//  4: n<512: p0 = ckv fp32 [m][512] (clamped) + p1 = ckf fp16 [m][512];
//     n>=512: p2 = krr fp32 [m][256]                  -- fused c_kv split
// Layouts [m89/m91 verified]: A-frag A[m=lane&15][k=quad*8+j];
// B-frag B[n=lane&15][k=quad*8+j]; C/D col=lane&15, row=quad*4+reg.
// ---------------------------------------------------------------------------
__global__ __launch_bounds__(256) void gemm_f16(const _Float16* __restrict__ A, int lda,
                                                const _Float16* __restrict__ Bt,
                                                void* __restrict__ p0,
                                                void* __restrict__ p1,
                                                void* __restrict__ p2,
                                                float cscale, int mode,
                                                int N, int K) {
    __shared__ __align__(16) _Float16 lA[128 * 32];
    __shared__ __align__(16) _Float16 lB[128 * 32];
    const int t = threadIdx.x, lane = t & 63, w = t >> 6;
    const int quad = lane >> 4, l16 = lane & 15;
    const int wr = w >> 1, wc = w & 1;
    const int m0 = blockIdx.y * 128, n0 = blockIdx.x * 128;
    f32x4 acc[4][4] = {};

    for (int kt = 0; kt < K; kt += 32) {
        __syncthreads();
#pragma unroll
        for (int c = 0; c < 2; ++c) {
            const int chunk = c * 256 + t;
            const int row = chunk >> 2, co = (chunk & 3) * 8;
            const int lofs = (c * 256 + w * 64) * 8;   // fp16 units, wave-uniform
            gload16(A + (size_t)(m0 + row) * lda + kt + co, lA + lofs);
            gload16(Bt + (size_t)(n0 + row) * K + kt + co, lB + lofs);
        }
        __syncthreads();
        half8 af[4], bf4[4];
#pragma unroll
        for (int i = 0; i < 4; ++i) {
            af[i]  = *(const half8*)&lA[(wr * 64 + i * 16 + l16) * 32 + quad * 8];
            bf4[i] = *(const half8*)&lB[(wc * 64 + i * 16 + l16) * 32 + quad * 8];
        }
#pragma unroll
        for (int i = 0; i < 4; ++i)
#pragma unroll
            for (int j = 0; j < 4; ++j)
                acc[i][j] = __builtin_amdgcn_mfma_f32_16x16x32_f16(af[i], bf4[j], acc[i][j], 0, 0, 0);
    }
#pragma unroll
    for (int i = 0; i < 4; ++i)
#pragma unroll
        for (int j = 0; j < 4; ++j) {
            const int mbase = m0 + wr * 64 + i * 16 + quad * 4;
            const int nn = n0 + wc * 64 + j * 16 + l16;
            if (mode == 0) {
                float* C = (float*)p0;
#pragma unroll
                for (int r = 0; r < 4; ++r)
                    C[(size_t)(mbase + r) * N + nn] = cl(acc[i][j][r]);
            } else if (mode == 1) {
                _Float16* Cf = (_Float16*)p0;
#pragma unroll
                for (int r = 0; r < 4; ++r)
                    Cf[(size_t)(mbase + r) * N + nn] = (_Float16)acc[i][j][r];
            } else if (mode == 2) {
                u16* Q = (u16*)p0;
                const int h = nn >> 7, dcol = nn & 127;
#pragma unroll
                for (int r = 0; r < 4; ++r)
                    Q[(size_t)(mbase + r) * 3072 + h * 192 + dcol] =
                        f2b(acc[i][j][r] * cscale);
            } else if (mode == 3) {
                const int bb = mbase >> 11, s = mbase & 2047;
                if (nn < 512) {
                    u16* Kp = (u16*)p0;
                    const int kv = nn >> 7, d = nn & 127;
                    const size_t rb = ((size_t)((bb * 4 + kv) * 2048 + s)) * 192 + d;
#pragma unroll
                    for (int r = 0; r < 4; ++r)
                        Kp[rb + (size_t)r * 192] = f2b(acc[i][j][r]);
                } else {
                    u16* Vt = (u16*)p1;
                    const int e = nn - 512, kv = e >> 7, d = e & 127;
                    u16x4 pk;
                    pk[0] = f2b(acc[i][j][0]); pk[1] = f2b(acc[i][j][1]);
                    pk[2] = f2b(acc[i][j][2]); pk[3] = f2b(acc[i][j][3]);
                    *(u16x4*)&((u16*)Vt)[((size_t)((bb * 4 + kv) * 128 + d)) * 2048 + s] = pk;
                }
            } else {   // mode 4
                if (nn < 512) {
                    float* ckv = (float*)p0;
                    _Float16* ckf = (_Float16*)p1;
#pragma unroll
                    for (int r = 0; r < 4; ++r) {
                        float v = acc[i][j][r];
                        ckv[(size_t)(mbase + r) * 512 + nn] = cl(v);
                        ckf[(size_t)(mbase + r) * 512 + nn] = (_Float16)v;
                    }
                } else {
                    float* krr = (float*)p2;
#pragma unroll
                    for (int r = 0; r < 4; ++r)
                        krr[(size_t)(mbase + r) * 256 + (nn - 512)] = acc[i][j][r];
                }
            }
        }
}

// ---------------------------------------------------------------------------
// RoPE Q: dqr fp16 [(b,s)][2560] cols 1536.. -> qb16 bf16 [(b,s)][h*192+128+d],
// pre-scaled by 1/sqrt(192).
// ---------------------------------------------------------------------------
__global__ __launch_bounds__(256) void rope_q16(const _Float16* __restrict__ dqr,
                                                const float* __restrict__ cosc,
                                                const float* __restrict__ sinc,
                                                const int* __restrict__ pos,
                                                u16* __restrict__ qb16) {
    const float sc = 0.07216878364870322f;           // 1/sqrt(192)
    int t = blockIdx.x * 256 + threadIdx.x;          // t < 4096*16*32
    int d = t & 31, h = (t >> 5) & 15, rowi = t >> 9;
    int s = rowi & 2047;
    int p = pos[s];
    float c1 = cosc[p * 64 + d],      s1 = sinc[p * 64 + d];
    float c2 = cosc[p * 64 + 32 + d], s2 = sinc[p * 64 + 32 + d];
    const _Float16* base = dqr + (size_t)rowi * 2560 + 1536 + h * 64;
    float x1 = (float)base[d];
    float x2 = (float)base[d + 32];
    u16* q = qb16 + (size_t)rowi * 3072 + h * 192 + 128;
    q[d]      = f2b((x1 * c1 - x2 * s1) * sc);
    q[d + 32] = f2b((x2 * c2 + x1 * s2) * sc);
}

// RoPE K: krr fp32 [(b,s)][256] -> Krope fp32 (Output 2) + Kp bf16 cols 128..191
__global__ __launch_bounds__(256) void rope_k(const float* __restrict__ krr,
                                              const float* __restrict__ cosc,
                                              const float* __restrict__ sinc,
                                              const int* __restrict__ pos,
                                              float* __restrict__ Krope,
                                              u16* __restrict__ Kp) {
    int t = blockIdx.x * 256 + threadIdx.x;          // t < 4096*4*32
    int d = t & 31, kv = (t >> 5) & 3, rowi = t >> 7;
    int b = rowi >> 11, s = rowi & 2047;
    int p = pos[s];
    float c1 = cosc[p * 64 + d],      s1 = sinc[p * 64 + d];
    float c2 = cosc[p * 64 + 32 + d], s2 = sinc[p * 64 + 32 + d];
    float x1 = krr[(size_t)rowi * 256 + kv * 64 + d];
    float x2 = krr[(size_t)rowi * 256 + kv * 64 + 32 + d];
    float o1 = x1 * c1 - x2 * s1;
    float o2 = x2 * c2 + x1 * s2;
    int g = b * NKV_ + kv;
    size_t ob = ((size_t)(g * S_) + s) * 64;
    Krope[ob + d]      = cl(o1);
    Krope[ob + 32 + d] = cl(o2);
    u16* kp = Kp + ((size_t)(g * S_ + s)) * 192 + 128;
    kp[d]      = f2b(o1);
    kp[32 + d] = f2b(o2);
}

// ---------------------------------------------------------------------------
// MFMA flash attention. Block = 4 waves = 64 q-rows of one (b,h).
// Paired q-tiles: qt = 31-px then px -> 33 kv-tile units per block, uniform.
// Flat grid 512; id decode puts the 64 blocks of each KV group g on one XCD
// (id&7 == g, round-robin block->XCD) so K/V (~1.3MB/g) stay in the 4MB L2.
// Row-sum l computed FREE via a bf16-ones d-row (row 128) in lVt: PV's 9th
// n-chunk accumulates l into O9[8] (rescaled together with O). Defer-max
// (T13, THR=8) skips the O-rescale when the tile max grows <= 8.
// Q from qb16 bf16 [(b,s)][h*192+k], pre-scaled by 1/sqrt(192).
// Out: atf fp16 [(b,s)][h*128+d].
// Layouts [m89/m91 verified]: A-frag A[m=lane&15][k=quad*8+j];
// B-frag B[n=lane&15][k=quad*8+j]; C/D col=lane&15, row=quad*4+reg.
// ---------------------------------------------------------------------------
__global__ __launch_bounds__(256) void attn_mfma(const u16* __restrict__ qb16,
                                                 const u16* __restrict__ Kp,
                                                 const u16* __restrict__ Vt,
                                                 _Float16* __restrict__ atf) {
    __shared__ __align__(16) u16 lK[64 * 200];     // 64 kv-rows x 192 (+8 pad)
    __shared__ __align__(16) u16 lVt[144 * 72];    // 128 d-rows + 16 (ones) x 64 (+8 pad)
    __shared__ __align__(16) u16 lP[4][16 * 72];   // per-wave P 16x64 (+8 pad)

    const int t = threadIdx.x, lane = t & 63, w = t >> 6;
    const int quad = lane >> 4, l16 = lane & 15;
    // XCD-aligned decode: g = id&7 so all blocks of a KV group share an XCD
    const int id = blockIdx.x;                     // 0..511
    const int g = id & 7;                          // (b*4 + kv)
    const int b = g >> 2;
    const int k = id >> 3;                         // 0..63
    const int h = (g & 3) * 4 + (k & 3);
    const int px = k >> 2;                         // 0..15

    // ones-row init for the l-column trick (rows 128..143, cols 0..63)
#pragma unroll
    for (int c = 0; c < 4; ++c) {
        int i = c * 256 + t;                       // 0..1023
        int rr = 128 + (i >> 6), ccol = i & 63;
        lVt[rr * 72 + ccol] = (rr == 128) ? (u16)0x3F80 : (u16)0;
    }

    for (int ph = 0; ph < 2; ++ph) {
        const int qt = ph ? px : (31 - px);        // heavy tile first
        const int q0 = qt * 64;
        const int iw = q0 + w * 16;                // wave's q-row base

        // Q fragments: rows m=l16, contiguous 192-col row (pre-scaled bf16)
        short8 qf[6];
        {
            const u16* qp = qb16 + ((size_t)(b * S_ + iw + l16)) * 3072 + h * 192;
#pragma unroll
            for (int kc = 0; kc < 6; ++kc)
                qf[kc] = *(const short8*)&qp[kc * 32 + quad * 8];
        }

        f32x4 O9[9] = {};                          // [0..7]=O d-chunks, [8]=l (col l16==0)
        float mr[4] = {-1e30f, -1e30f, -1e30f, -1e30f};

        const int ntile = qt + 1;
        for (int tile = 0; tile < ntile; ++tile) {
            const int j0 = tile * 64;
            __syncthreads();
            // stage K tile: 64 rows x 192 u16 = 1536 x 16B, 6/thread
#pragma unroll
            for (int c = 0; c < 6; ++c) {
                int seg = c * 256 + t;
                int row = seg / 24, ch = (seg % 24) * 8;
                *(uint4*)&lK[row * 200 + ch] =
                    *(const uint4*)&Kp[((size_t)g * S_ + j0 + row) * 192 + ch];
            }
            // stage Vt tile: 128 d-rows x 64 u16 = 1024 x 16B, 4/thread
#pragma unroll
            for (int c = 0; c < 4; ++c) {
                int seg = c * 256 + t;
                int d = seg >> 3, ch = (seg & 7) * 8;
                *(uint4*)&lVt[d * 72 + ch] =
                    *(const uint4*)&Vt[((size_t)g * 128 + d) * S_ + j0 + ch];
            }
            __syncthreads();

            // S = Q K^T, four 16-col chunks
            f32x4 s4[4];
            __builtin_amdgcn_s_setprio(1);
#pragma unroll
            for (int cc = 0; cc < 4; ++cc) {
                f32x4 sx = {};
#pragma unroll
                for (int kc = 0; kc < 6; ++kc) {
                    short8 kf = *(const short8*)&lK[(cc * 16 + l16) * 200 + kc * 32 + quad * 8];
                    sx = __builtin_amdgcn_mfma_f32_16x16x32_bf16(qf[kc], kf, sx, 0, 0, 0);
                }
                s4[cc] = sx;
            }
            __builtin_amdgcn_s_setprio(0);

            // causal mask; rows ir = iw + quad*4 + r, cols j0 + cc*16 + l16
            float sv[4][4];
#pragma unroll
            for (int cc = 0; cc < 4; ++cc)
#pragma unroll
                for (int r = 0; r < 4; ++r) {
                    int ir = iw + quad * 4 + r;
                    sv[cc][r] = (j0 + cc * 16 + l16 <= ir) ? s4[cc][r] : -1e30f;
                }
            // row max across the 16-lane group
            float tm[4];
#pragma unroll
            for (int r = 0; r < 4; ++r)
                tm[r] = fmaxf(fmaxf(sv[0][r], sv[1][r]), fmaxf(sv[2][r], sv[3][r]));
#pragma unroll
            for (int m = 1; m < 16; m <<= 1)
#pragma unroll
                for (int r = 0; r < 4; ++r) tm[r] = fmaxf(tm[r], __shfl_xor(tm[r], m));
            // defer-max: only rescale when the max grew by > 8
            int small = (tm[0] <= mr[0] + 8.f) && (tm[1] <= mr[1] + 8.f) &&
                        (tm[2] <= mr[2] + 8.f) && (tm[3] <= mr[3] + 8.f);
            if (!__all(small)) {
                float al[4];
#pragma unroll
                for (int r = 0; r < 4; ++r) {
                    float mn = fmaxf(mr[r], tm[r]);
                    al[r] = __expf(mr[r] - mn);
                    mr[r] = mn;
                }
#pragma unroll
                for (int dc = 0; dc < 9; ++dc)
#pragma unroll
                    for (int r = 0; r < 4; ++r) O9[dc][r] *= al[r];
            }
            // P = exp(S - mr)  (bounded by e^8 when deferred)
            float p[4][4];
#pragma unroll
            for (int cc = 0; cc < 4; ++cc)
#pragma unroll
                for (int r = 0; r < 4; ++r)
                    p[cc][r] = __expf(sv[cc][r] - mr[r]);
            // P (C layout) -> LDS -> A-layout frags (k = 0..31, 32..63)
#pragma unroll
            for (int cc = 0; cc < 4; ++cc)
#pragma unroll
                for (int r = 0; r < 4; ++r)
                    lP[w][(quad * 4 + r) * 72 + cc * 16 + l16] = f2b(p[cc][r]);
            short8 pf0 = *(const short8*)&lP[w][l16 * 72 + quad * 8];
            short8 pf1 = *(const short8*)&lP[w][l16 * 72 + 32 + quad * 8];
            // O += P V ; 9th chunk accumulates l via the ones-row
            __builtin_amdgcn_s_setprio(1);
#pragma unroll
            for (int dc = 0; dc < 9; ++dc) {
                short8 vf0 = *(const short8*)&lVt[(dc * 16 + l16) * 72 + quad * 8];
                short8 vf1 = *(const short8*)&lVt[(dc * 16 + l16) * 72 + 32 + quad * 8];
                O9[dc] = __builtin_amdgcn_mfma_f32_16x16x32_bf16(pf0, vf0, O9[dc], 0, 0, 0);
                O9[dc] = __builtin_amdgcn_mfma_f32_16x16x32_bf16(pf1, vf1, O9[dc], 0, 0, 0);
            }
            __builtin_amdgcn_s_setprio(0);
        }
        // epilogue: l lives in O9[8] at col l16==0; broadcast within quad
        float inv[4];
#pragma unroll
        for (int r = 0; r < 4; ++r) {
            float lr = __shfl(O9[8][r], quad * 16);
            inv[r] = 1.f / fmaxf(lr, 1e-30f);
        }
#pragma unroll
        for (int dc = 0; dc < 8; ++dc)
#pragma unroll
            for (int r = 0; r < 4; ++r) {
                int ir = iw + quad * 4 + r;
                atf[((size_t)(b * S_ + ir)) * 2048 + h * 128 + dc * 16 + l16] =
                    (_Float16)cl(O9[dc][r] * inv[r]);
            }
    }
}

// ---------------------------------------------------------------------------
extern "C" void kernel_launch(void* const* d_in, const int* in_sizes, int n_in,
                              void* d_out, int out_size, void* d_ws, size_t ws_size,
                              hipStream_t stream) {
    const float* x     = (const float*)d_in[0];
    const float* cosc  = (const float*)d_in[1];
    const float* sinc  = (const float*)d_in[2];
    const int*   pos   = (const int*)d_in[3];
    // d_in[4] = attn_mask (causal tril) -- implemented analytically
    const float* W_DKV = (const float*)d_in[5];
    const float* W_UK  = (const float*)d_in[6];
    const float* W_UV  = (const float*)d_in[7];
    const float* W_DQ  = (const float*)d_in[8];
    const float* W_UQ  = (const float*)d_in[9];
    const float* W_KR  = (const float*)d_in[10];
    const float* W_QR  = (const float*)d_in[11];
    const float* W_O   = (const float*)d_in[12];
    (void)ws_size;

    float* outp      = (float*)d_out;            // [B,S,2048]
    float* ckv_out   = outp + 8388608;           // [B,S,512]
    float* krope_out = outp + 10485760;          // [B,NKV,S,64]

    // ---- workspace (~128 MB) ----
    char* w = (char*)d_ws;
    auto alloc = [&](size_t bytes) { char* p = w; w += bytes; return p; };
    _Float16* xf   = (_Float16*)alloc(16777216);  // x fp16 [4096][2048]
    _Float16* ckf  = (_Float16*)alloc(4194304);   // c_kv fp16 [4096][512]
    float*    krr  = (float*)alloc(4194304);      // K-rope raw fp32 [4096][256]
    _Float16* dqr  = (_Float16*)alloc(20971520);  // c_q | q_rope_raw fp16 [4096][2560]
    u16*      qb16 = (u16*)alloc(25165824);       // Q bf16 pre-scaled [4096][16][192]
    u16*      Kp   = (u16*)alloc(6291456);        // [8][2048][192] bf16
    u16*      Vt   = (u16*)alloc(4194304);        // [8][128][2048] bf16
    _Float16* atf  = (_Float16*)alloc(16777216);  // attn out fp16 [4096][2048]
    _Float16* Wdkr = (_Float16*)alloc(3145728);   // [768][2048]  (DKV|KR)
    _Float16* Wdqr = (_Float16*)alloc(10485760);  // [2560][2048] (DQ|QR)
    _Float16* Wuq  = (_Float16*)alloc(6291456);   // [2048][1536]
    _Float16* Wukv = (_Float16*)alloc(1048576);   // [1024][512]  (UK|UV)
    _Float16* Wo   = (_Float16*)alloc(8388608);   // [2048][2048]

    const float sc = 0.07216878364870322f;        // 1/sqrt(192)
    const dim3 tb(32, 8);

    // input / weight prep (fp16)
    x_f16<<<4096, 256, 0, stream>>>(x, xf);
    wt_f16<<<dim3(64, 16), tb, 0, stream>>>(W_DKV, Wdkr, 2048, 512);
    wt_f16<<<dim3(64, 8),  tb, 0, stream>>>(W_KR,  Wdkr + (size_t)512 * 2048, 2048, 256);
    wt_f16<<<dim3(64, 48), tb, 0, stream>>>(W_DQ,  Wdqr, 2048, 1536);
    wt_f16<<<dim3(64, 32), tb, 0, stream>>>(W_QR,  Wdqr + (size_t)1536 * 2048, 2048, 1024);
    wt_f16<<<dim3(48, 64), tb, 0, stream>>>(W_UQ,  Wuq, 1536, 2048);
    wt_f16<<<dim3(16, 16), tb, 0, stream>>>(W_UK,  Wukv, 512, 512);
    wt_f16<<<dim3(16, 16), tb, 0, stream>>>(W_UV,  Wukv + (size_t)512 * 512, 512, 512);
    wt_f16<<<dim3(64, 64), tb, 0, stream>>>(W_O,   Wo, 2048, 2048);

    // c_kv (Output 1, fp32) + ckf fp16 + K-rope-raw, one fused GEMM
    gemm_f16<<<dim3(6, 32), 256, 0, stream>>>(xf, 2048, Wdkr,
                                              ckv_out, ckf, krr, 1.f, 4, 768, 2048);
    // c_q | q_rope_raw, one merged GEMM
    gemm_f16<<<dim3(20, 32), 256, 0, stream>>>(xf, 2048, Wdqr,
                                               dqr, nullptr, nullptr, 1.f, 1, 2560, 2048);
    // Q content -> qb16 (bf16, pre-scaled)
    gemm_f16<<<dim3(16, 32), 256, 0, stream>>>(dqr, 2560, Wuq,
                                               qb16, nullptr, nullptr, sc, 2, 2048, 1536);
    // K content -> Kp cols 0..127 and V -> Vt, fused pack/transpose
    gemm_f16<<<dim3(8, 32), 256, 0, stream>>>(ckf, 512, Wukv,
                                              Kp, Vt, nullptr, 1.f, 3, 1024, 512);

    // rope: Q -> qb16 cols 128..191; K -> Output 2 + Kp cols 128..191
    rope_q16<<<8192, 256, 0, stream>>>(dqr, cosc, sinc, pos, qb16);
    rope_k<<<2048, 256, 0, stream>>>(krr, cosc, sinc, pos, krope_out, Kp);

    // attention + output projection
    attn_mfma<<<512, 256, 0, stream>>>(qb16, Kp, Vt, atf);
    gemm_f16<<<dim3(16, 32), 256, 0, stream>>>(atf, 2048, Wo,
                                               outp, nullptr, nullptr, 1.f, 0, 2048, 2048);
}